// Round 1
// baseline (112.953 us; speedup 1.0000x reference)
//
#include <hip/hip_runtime.h>

#define NPAIR   144      // 12*12 mic pairs
#define KLEN    512      // GCC window length
#define GPTS    2048     // 32*64 grid points
#define NFRAMES 256      // B*T = 8*32
#define STAGE   16       // rows staged in LDS per barrier (16*512*4B = 32 KiB)
#define EPSV    1e-12f

// Pre-pass: pack tau0 (int32, values in [0,512)) into uint16 with the
// stage-local row offset folded in: (pair % STAGE)*KLEN + tau  (< 8192).
// Halves index traffic vs int32 and makes the LDS gather address a single shl.
__global__ void pack_tau_kernel(const int* __restrict__ tau0,
                                unsigned short* __restrict__ tau16, int n) {
    int i = blockIdx.x * 256 + threadIdx.x;
    if (i < n) {
        int pair = i >> 11;  // i / GPTS
        tau16[i] = (unsigned short)(((pair & (STAGE - 1)) << 9) + tau0[i]);
    }
}

// One block per frame (256 blocks = 1 per CU), 1024 threads (16 waves/CU).
// Each thread owns grid points g = 2t, 2t+1 (indices load as one dword).
__global__ __launch_bounds__(1024)
void srp_map_kernel(const float* __restrict__ x,
                    const unsigned short* __restrict__ tau16,
                    float* __restrict__ out) {
    __shared__ float rows[STAGE * KLEN];   // 32 KiB
    __shared__ float red[17];

    const int f = blockIdx.x;
    const int t = threadIdx.x;
    const float* xf = x + (size_t)f * (NPAIR * KLEN);

    float acc0 = 0.0f, acc1 = 0.0f;
    const int g0 = t << 1;

    for (int s = 0; s < NPAIR / STAGE; ++s) {   // 9 stages
        // Stage 16 rows = 8192 floats with 1024 threads: 2 x float4 each.
        const float4* src = (const float4*)(xf + s * (STAGE * KLEN));
        float4* dst = (float4*)rows;
        dst[t]        = src[t];
        dst[t + 1024] = src[t + 1024];
        __syncthreads();

        const unsigned short* tp = tau16 + s * (STAGE * GPTS) + g0;
        #pragma unroll
        for (int p = 0; p < STAGE; ++p) {
            unsigned idx2 = *(const unsigned*)(tp + p * GPTS);  // 2 packed u16
            acc0 += rows[idx2 & 0xffffu];
            acc1 += rows[idx2 >> 16];
        }
        __syncthreads();
    }

    const int wave = t >> 6;
    const int lane = t & 63;

    // --- block mean over 2048 values ---
    float sm = acc0 + acc1;
    #pragma unroll
    for (int off = 32; off > 0; off >>= 1) sm += __shfl_down(sm, off, 64);
    if (lane == 0) red[wave] = sm;
    __syncthreads();
    if (t == 0) {
        float tot = 0.0f;
        #pragma unroll
        for (int w = 0; w < 16; ++w) tot += red[w];
        red[16] = tot * (1.0f / (float)GPTS);
    }
    __syncthreads();
    const float mean = red[16];

    const float v0 = acc0 - mean + EPSV;
    const float v1 = acc1 - mean + EPSV;

    // --- block max over shifted values ---
    float mx = fmaxf(v0, v1);
    #pragma unroll
    for (int off = 32; off > 0; off >>= 1) mx = fmaxf(mx, __shfl_down(mx, off, 64));
    __syncthreads();              // red[0..15] reads above done before re-write
    if (lane == 0) red[wave] = mx;
    __syncthreads();
    if (t == 0) {
        float mm = red[0];
        #pragma unroll
        for (int w = 1; w < 16; ++w) mm = fmaxf(mm, red[w]);
        red[16] = mm;
    }
    __syncthreads();
    const float maxv = red[16];

    float2 o;
    o.x = v0 / maxv;
    o.y = v1 / maxv;
    ((float2*)(out + (size_t)f * GPTS))[t] = o;
}

extern "C" void kernel_launch(void* const* d_in, const int* in_sizes, int n_in,
                              void* d_out, int out_size, void* d_ws, size_t ws_size,
                              hipStream_t stream) {
    const float* x    = (const float*)d_in[0];
    const int*   tau0 = (const int*)d_in[1];
    unsigned short* tau16 = (unsigned short*)d_ws;   // 144*2048*2 B = 576 KiB
    float* out = (float*)d_out;

    const int n = NPAIR * GPTS;
    pack_tau_kernel<<<(n + 255) / 256, 256, 0, stream>>>(tau0, tau16, n);
    srp_map_kernel<<<NFRAMES, 1024, 0, stream>>>(x, tau16, out);
}